// Round 10
// baseline (143.535 us; speedup 1.0000x reference)
//
#include <hip/hip_runtime.h>
#include <hip/hip_bf16.h>

typedef unsigned short u16;
typedef unsigned int u32;
typedef float f32x4 __attribute__((ext_vector_type(4)));

#define N_ROWS 8192
#define DIM 512
#define BM 128
#define BN 128
#define NREP 8             // accumulator replicas
#define NTILES 2080        // 32 pairs * 65 tiles = full upper triangle
// sqrt(log2(e)/0.07): folded into stored fp8 so MFMA emits sim/T*log2(e)
// directly and the epilogue uses raw v_exp_f32 (exp2) with no extra mul.
#define SCALE 4.5398160f

// ------- kernel 1: L2-normalize rows -> fp8 e4m3 (pre-scaled); zero accs ---
__global__ __launch_bounds__(256) void norm_cast_kernel(
        const float* __restrict__ x, u32* __restrict__ hb8,
        float* __restrict__ accR /* 2*NREP*N_ROWS floats */,
        float* __restrict__ out) {
    int gid = blockIdx.x * 256 + threadIdx.x;
    if (gid < 2 * NREP * N_ROWS) accR[gid] = 0.f;
    if (gid == 0) out[0] = 0.f;
    int row  = blockIdx.x * 4 + (threadIdx.x >> 6);
    int lane = threadIdx.x & 63;
    const float4* xr = (const float4*)(x + (size_t)row * DIM);
    float4 v0 = xr[lane * 2 + 0];
    float4 v1 = xr[lane * 2 + 1];
    float ss = v0.x * v0.x + v0.y * v0.y + v0.z * v0.z + v0.w * v0.w
             + v1.x * v1.x + v1.y * v1.y + v1.z * v1.z + v1.w * v1.w;
#pragma unroll
    for (int off = 32; off; off >>= 1) ss += __shfl_xor(ss, off);
    float s = SCALE / fmaxf(sqrtf(ss), 1e-12f);
    // pack 8 fp8 (OCP e4m3 on gfx950, RNE+sat in HW)
    int w0 = __builtin_amdgcn_cvt_pk_fp8_f32(v0.x * s, v0.y * s, 0, false);
    w0     = __builtin_amdgcn_cvt_pk_fp8_f32(v0.z * s, v0.w * s, w0, true);
    int w1 = __builtin_amdgcn_cvt_pk_fp8_f32(v1.x * s, v1.y * s, 0, false);
    w1     = __builtin_amdgcn_cvt_pk_fp8_f32(v1.z * s, v1.w * s, w1, true);
    uint2 o; o.x = (u32)w0; o.y = (u32)w1;
    ((uint2*)((char*)hb8 + (size_t)row * DIM + lane * 8))[0] = o;
}

// stage helper: immediate offset must be a constant-expression for
// __builtin_amdgcn_global_load_lds -> template parameter.
template <int K0OFF>
__device__ __forceinline__ void stage_tiles(
        const char* const* gA, const char* const* gB,
        char* ldsA, char* ldsB, int tid) {
#pragma unroll
    for (int s2 = 0; s2 < 4; ++s2) {
        int seg = tid + s2 * 256;
        __builtin_amdgcn_global_load_lds(
            (const __attribute__((address_space(1))) void*)gA[s2],
            (__attribute__((address_space(3))) void*)&ldsA[seg * 16],
            16, K0OFF, 0);
        __builtin_amdgcn_global_load_lds(
            (const __attribute__((address_space(1))) void*)gB[s2],
            (__attribute__((address_space(3))) void*)&ldsB[seg * 16],
            16, K0OFF, 0);
    }
}

// epilogue sums, specialized on diagonal-ness. Off-diag tiles (2016/2080)
// can NEVER hit the self-pair exclusion (|colBase-rowBase| >= 128 while
// |rloc-cloc| < 128), so the per-element diff-compare is diag-only.
template <bool DIAG>
__device__ __forceinline__ void epilogue_sums(
        f32x4 (&acc)[4][4], const int* labR, const int* labC,
        float (*cT)[BN], float (*cP)[BN], float (*rT)[BM], float (*rP)[BM],
        int wm, int wn, int wr, int wc, int quad, int l16) {
    int lc[4];
#pragma unroll
    for (int in = 0; in < 4; ++in) lc[in] = labC[wn + in * 16 + l16];

    float colT[4] = {0.f, 0.f, 0.f, 0.f}, colP[4] = {0.f, 0.f, 0.f, 0.f};
#pragma unroll
    for (int im = 0; im < 4; ++im) {
        float rowT[4] = {0.f, 0.f, 0.f, 0.f}, rowP[4] = {0.f, 0.f, 0.f, 0.f};
#pragma unroll
        for (int reg = 0; reg < 4; ++reg) {
            int rloc = wm + im * 16 + quad * 4 + reg;
            int li = labR[rloc];
#pragma unroll
            for (int in = 0; in < 4; ++in) {
                int cloc = wn + in * 16 + l16;
                float e = __builtin_exp2f(acc[im][in][reg]);  // v_exp_f32
                bool pos = (lc[in] == li);
                if (DIAG) pos = pos && (rloc != cloc);
                colT[in] += e; rowT[reg] += e;
                if (pos) { colP[in] += e; rowP[reg] += e; }
            }
        }
        if (!DIAG) {
#pragma unroll
            for (int reg = 0; reg < 4; ++reg) {
                float tt = rowT[reg], pp = rowP[reg];
                tt += __shfl_xor(tt, 1); tt += __shfl_xor(tt, 2);
                tt += __shfl_xor(tt, 4); tt += __shfl_xor(tt, 8);
                pp += __shfl_xor(pp, 1); pp += __shfl_xor(pp, 2);
                pp += __shfl_xor(pp, 4); pp += __shfl_xor(pp, 8);
                if (l16 == 0) {
                    int rloc = wm + im * 16 + quad * 4 + reg;
                    rT[wc][rloc] = tt;
                    rP[wc][rloc] = pp;
                }
            }
        }
    }
#pragma unroll
    for (int in = 0; in < 4; ++in) {
        float tt = colT[in], pp = colP[in];
        tt += __shfl_xor(tt, 16); tt += __shfl_xor(tt, 32);
        pp += __shfl_xor(pp, 16); pp += __shfl_xor(pp, 32);
        if (quad == 0) {
            int cloc = wn + in * 16 + l16;
            cT[wr][cloc] = tt;
            cP[wr][cloc] = pp;
        }
    }
}

// ------- kernel 2: triangular fused tile GEMM (fp8) + exp2 + sums ----------
// R2/R9-MEASURED core (51.4us tile): stage -> sync -> compute -> sync, fp8
// 16x16x32 MFMA, XOR-swizzled LDS, launch_bounds(256,4) -> VGPR 64, 4 blk/CU.
// NEW this round: (a) exact grid 2080 (no dead blocks) with XCD-chunked
// swizzle s=(b&7)*260+(b>>3) — 260=4*65 whole pairs per XCD, ~512KB L2 set;
// (b) DIAG-templated epilogue (identity transform, saves diff-cmp off-diag).
__global__ __launch_bounds__(256, 4) void tile_kernel(
        const char* __restrict__ hb8, const int* __restrict__ labels,
        float* __restrict__ rowTotalR, float* __restrict__ rowPosR) {
    __shared__ __align__(16) char ldsA[BM * 128];   // 16 KB
    __shared__ __align__(16) char ldsB[BN * 128];   // 16 KB
    __shared__ int labR[BM];
    __shared__ int labC[BN];
    __shared__ float cT[2][BN], cP[2][BN];
    __shared__ float rT[2][BM], rP[2][BM];

    const int b = blockIdx.x;                 // 0..2079
    const int s = (b & 7) * 260 + (b >> 3);   // XCD-chunked tile id
    const int p = s / 65;                     // pair id [0,32)
    const int t = s - p * 65;                 // tile within pair [0,65)
    int ti, tj;
    if (t <= p) { tj = p; ti = t; }
    else        { tj = 63 - p; ti = t - p - 1; }

    const int rowBase = ti * BM;
    const int colBase = tj * BN;
    const bool isDiag = (ti == tj);
    const int rep = (ti + tj) & (NREP - 1);
    const int tid = threadIdx.x;

    if (tid < 128) labR[tid] = labels[rowBase + tid];
    else           labC[tid - 128] = labels[colBase + tid - 128];

    const int w = tid >> 6;
    const int lane = tid & 63;
    const int wm = (w >> 1) * 64;
    const int wn = (w & 1) * 64;
    const int wr = w >> 1;
    const int wc = w & 1;
    const int quad = lane >> 4;
    const int l16 = lane & 15;

    // staging bases (computed once; k0 advances via immediate offset)
    const char* gA[4]; const char* gB[4];
#pragma unroll
    for (int s2 = 0; s2 < 4; ++s2) {
        int seg = tid + s2 * 256;         // 0..1023
        int r = seg >> 3;                 // 0..127
        int sl = seg & 7;                 // LDS 16-B slot
        int g = sl ^ (r & 7);             // global 16-B chunk within 128-B row-slice
        gA[s2] = hb8 + (size_t)(rowBase + r) * DIM + g * 16;
        gB[s2] = hb8 + (size_t)(colBase + r) * DIM + g * 16;
    }

    f32x4 acc[4][4];
#pragma unroll
    for (int i = 0; i < 4; ++i)
#pragma unroll
        for (int jj = 0; jj < 4; ++jj)
            acc[i][jj] = (f32x4){0.f, 0.f, 0.f, 0.f};

#pragma unroll
    for (int k0 = 0; k0 < 4; ++k0) {      // BK=128 bytes, imm offset k0*128
        switch (k0) {
            case 0: stage_tiles<0>(gA, gB, ldsA, ldsB, tid); break;
            case 1: stage_tiles<128>(gA, gB, ldsA, ldsB, tid); break;
            case 2: stage_tiles<256>(gA, gB, ldsA, ldsB, tid); break;
            default: stage_tiles<384>(gA, gB, ldsA, ldsB, tid); break;
        }
        __syncthreads();                  // drain + barrier
#pragma unroll
        for (int kk = 0; kk < 4; ++kk) {  // four K=32 MFMA steps per BK=128
            long af[4], bfr[4];
#pragma unroll
            for (int im = 0; im < 4; ++im) {
                int row = wm + im * 16 + l16;
                int c4 = kk * 2 + (quad >> 1);
                int sl = c4 ^ (row & 7);
                af[im] = *(const long*)&ldsA[row * 128 + sl * 16 + (quad & 1) * 8];
            }
#pragma unroll
            for (int in = 0; in < 4; ++in) {
                int col = wn + in * 16 + l16;
                int c4 = kk * 2 + (quad >> 1);
                int sl = c4 ^ (col & 7);
                bfr[in] = *(const long*)&ldsB[col * 128 + sl * 16 + (quad & 1) * 8];
            }
#pragma unroll
            for (int im = 0; im < 4; ++im)
#pragma unroll
                for (int in = 0; in < 4; ++in)
                    acc[im][in] = __builtin_amdgcn_mfma_f32_16x16x32_fp8_fp8(
                        af[im], bfr[in], acc[im][in], 0, 0, 0);
        }
        __syncthreads();                  // protect buffers before next stage
    }

    // ---------------- epilogue (acc already = sim/T * log2e) ----------------
    if (isDiag) epilogue_sums<true >(acc, labR, labC, cT, cP, rT, rP, wm, wn, wr, wc, quad, l16);
    else        epilogue_sums<false>(acc, labR, labC, cT, cP, rT, rP, wm, wn, wr, wc, quad, l16);

    __syncthreads();
    float* rowTotal = rowTotalR + rep * N_ROWS;
    float* rowPos   = rowPosR   + rep * N_ROWS;
    if (tid < 128) {
        atomicAdd(&rowTotal[colBase + tid], cT[0][tid] + cT[1][tid]);
        if (!isDiag) atomicAdd(&rowTotal[rowBase + tid], rT[0][tid] + rT[1][tid]);
    } else {
        int t2 = tid - 128;
        atomicAdd(&rowPos[colBase + t2], cP[0][t2] + cP[1][t2]);
        if (!isDiag) atomicAdd(&rowPos[rowBase + t2], rP[0][t2] + rP[1][t2]);
    }
}

// ------- kernel 3: fold replicas + histogram + loss (64 blocks) ------------
__global__ __launch_bounds__(256) void reduce_loss_kernel(
        const int* __restrict__ labels, const float* __restrict__ rowTotalR,
        const float* __restrict__ rowPosR, float* __restrict__ out) {
    __shared__ int hist[128];
    __shared__ float red[256];
    int tid = threadIdx.x;
    if (tid < 128) hist[tid] = 0;
    __syncthreads();
    for (int i = tid; i < N_ROWS; i += 256)
        atomicAdd(&hist[labels[i] & 127], 1);
    __syncthreads();
    float sacc = 0.f;
    if (tid < 128) {
        int row = blockIdx.x * 128 + tid;
        float T = 0.f, P = 0.f;
#pragma unroll
        for (int r = 0; r < NREP; ++r) {
            T += rowTotalR[r * N_ROWS + row];
            P += rowPosR[r * N_ROWS + row];
        }
        float cc = (float)(hist[labels[row] & 127] - 1);
        sacc = logf((P / (cc + 1e-9f)) / T);
    }
    red[tid] = sacc;
    __syncthreads();
    for (int st = 128; st; st >>= 1) {
        if (tid < st) red[tid] += red[tid + st];
        __syncthreads();
    }
    if (tid == 0) atomicAdd(out, -red[0] / (float)N_ROWS);
}

extern "C" void kernel_launch(void* const* d_in, const int* in_sizes, int n_in,
                              void* d_out, int out_size, void* d_ws, size_t ws_size,
                              hipStream_t stream) {
    const float* hidden = (const float*)d_in[0];
    const int* labels   = (const int*)d_in[1];
    float* out = (float*)d_out;

    char* ws = (char*)d_ws;
    char* hb8 = ws;                                          // 8192*512 = 4 MB
    float* rowTotalR = (float*)(ws + (size_t)N_ROWS * DIM);  // NREP*8192 f
    float* rowPosR   = rowTotalR + NREP * N_ROWS;            // NREP*8192 f

    norm_cast_kernel<<<N_ROWS / 4, 256, 0, stream>>>(hidden, (u32*)hb8, rowTotalR, out);
    tile_kernel<<<NTILES, 256, 0, stream>>>(hb8, labels, rowTotalR, rowPosR);
    reduce_loss_kernel<<<64, 256, 0, stream>>>(labels, rowTotalR, rowPosR, out);
}

// Round 11
// 119.216 us; speedup vs baseline: 1.2040x; 1.2040x over previous
//
#include <hip/hip_runtime.h>
#include <hip/hip_bf16.h>

typedef unsigned short u16;
typedef unsigned int u32;
typedef float f32x4 __attribute__((ext_vector_type(4)));

#define N_ROWS 8192
#define DIM 512
#define BM 128
#define BN 128
#define NREP 8             // accumulator replicas
// sqrt(log2(e)/0.07): folded into stored fp8 so MFMA emits sim/T*log2(e)
// directly and the epilogue uses raw v_exp_f32 (exp2) with no extra mul.
#define SCALE 4.5398160f

// ------- kernel 1: L2-normalize rows -> fp8 e4m3 (pre-scaled); zero accs ---
__global__ __launch_bounds__(256) void norm_cast_kernel(
        const float* __restrict__ x, u32* __restrict__ hb8,
        float* __restrict__ accR /* 2*NREP*N_ROWS floats */,
        float* __restrict__ out) {
    int gid = blockIdx.x * 256 + threadIdx.x;
    if (gid < 2 * NREP * N_ROWS) accR[gid] = 0.f;
    if (gid == 0) out[0] = 0.f;
    int row  = blockIdx.x * 4 + (threadIdx.x >> 6);
    int lane = threadIdx.x & 63;
    const float4* xr = (const float4*)(x + (size_t)row * DIM);
    float4 v0 = xr[lane * 2 + 0];
    float4 v1 = xr[lane * 2 + 1];
    float ss = v0.x * v0.x + v0.y * v0.y + v0.z * v0.z + v0.w * v0.w
             + v1.x * v1.x + v1.y * v1.y + v1.z * v1.z + v1.w * v1.w;
#pragma unroll
    for (int off = 32; off; off >>= 1) ss += __shfl_xor(ss, off);
    float s = SCALE / fmaxf(sqrtf(ss), 1e-12f);
    // pack 8 fp8 (OCP e4m3 on gfx950, RNE+sat in HW)
    int w0 = __builtin_amdgcn_cvt_pk_fp8_f32(v0.x * s, v0.y * s, 0, false);
    w0     = __builtin_amdgcn_cvt_pk_fp8_f32(v0.z * s, v0.w * s, w0, true);
    int w1 = __builtin_amdgcn_cvt_pk_fp8_f32(v1.x * s, v1.y * s, 0, false);
    w1     = __builtin_amdgcn_cvt_pk_fp8_f32(v1.z * s, v1.w * s, w1, true);
    uint2 o; o.x = (u32)w0; o.y = (u32)w1;
    ((uint2*)((char*)hb8 + (size_t)row * DIM + lane * 8))[0] = o;
}

// stage helper: immediate offset must be a constant-expression for
// __builtin_amdgcn_global_load_lds -> template parameter.
template <int K0OFF>
__device__ __forceinline__ void stage_tiles(
        const char* const* gA, const char* const* gB,
        char* ldsA, char* ldsB, int tid) {
#pragma unroll
    for (int s2 = 0; s2 < 4; ++s2) {
        int seg = tid + s2 * 256;
        __builtin_amdgcn_global_load_lds(
            (const __attribute__((address_space(1))) void*)gA[s2],
            (__attribute__((address_space(3))) void*)&ldsA[seg * 16],
            16, K0OFF, 0);
        __builtin_amdgcn_global_load_lds(
            (const __attribute__((address_space(1))) void*)gB[s2],
            (__attribute__((address_space(3))) void*)&ldsB[seg * 16],
            16, K0OFF, 0);
    }
}

// ------- kernel 2: triangular fused tile GEMM (fp8) + exp2 + sums ----------
// R9-MEASURED optimum (51.4us tile, 118.8us total): stage -> sync -> compute
// -> sync per BK=128; launch_bounds(256,4) -> VGPR 64+64acc, 4 blocks/CU.
// R10 lesson: under the hard VGPR cap, epilogue code duplication (DIAG
// template) spilled to scratch silently (WRITE_SIZE 4->72MB) -> reverted.
__global__ __launch_bounds__(256, 4) void tile_kernel(
        const char* __restrict__ hb8, const int* __restrict__ labels,
        float* __restrict__ rowTotalR, float* __restrict__ rowPosR) {
    __shared__ __align__(16) char ldsA[BM * 128];   // 16 KB
    __shared__ __align__(16) char ldsB[BN * 128];   // 16 KB
    __shared__ int labR[BM];
    __shared__ int labC[BN];
    __shared__ float cT[2][BN], cP[2][BN];
    __shared__ float rT[2][BM], rP[2][BM];

    const int b = blockIdx.x;
    const int c = b & 255;          // CU slot (round-robin)
    const int m = b >> 8;           // step 0..8
    const int y = c >> 3;
    const int p = 4 * (c & 7) + (y & 3);    // pair id [0,32)
    const int j = y >> 2;                   // CU within pair [0,8)
    const int t = j + 8 * m;                // tile index within pair
    if (t >= 65) return;
    int ti, tj;
    if (t <= p) { tj = p; ti = t; }
    else        { tj = 63 - p; ti = t - p - 1; }

    const int rowBase = ti * BM;
    const int colBase = tj * BN;
    const bool isDiag = (ti == tj);
    const int dd = colBase - rowBase;
    const int rep = (ti + tj) & (NREP - 1);
    const int tid = threadIdx.x;

    if (tid < 128) labR[tid] = labels[rowBase + tid];
    else           labC[tid - 128] = labels[colBase + tid - 128];

    const int w = tid >> 6;
    const int lane = tid & 63;
    const int wm = (w >> 1) * 64;
    const int wn = (w & 1) * 64;
    const int wr = w >> 1;
    const int wc = w & 1;
    const int quad = lane >> 4;
    const int l16 = lane & 15;

    // staging bases (computed once; k0 advances via immediate offset)
    const char* gA[4]; const char* gB[4];
#pragma unroll
    for (int s2 = 0; s2 < 4; ++s2) {
        int seg = tid + s2 * 256;         // 0..1023
        int r = seg >> 3;                 // 0..127
        int sl = seg & 7;                 // LDS 16-B slot
        int g = sl ^ (r & 7);             // global 16-B chunk within 128-B row-slice
        gA[s2] = hb8 + (size_t)(rowBase + r) * DIM + g * 16;
        gB[s2] = hb8 + (size_t)(colBase + r) * DIM + g * 16;
    }

    f32x4 acc[4][4];
#pragma unroll
    for (int i = 0; i < 4; ++i)
#pragma unroll
        for (int jj = 0; jj < 4; ++jj)
            acc[i][jj] = (f32x4){0.f, 0.f, 0.f, 0.f};

#pragma unroll
    for (int k0 = 0; k0 < 4; ++k0) {      // BK=128 bytes, imm offset k0*128
        switch (k0) {
            case 0: stage_tiles<0>(gA, gB, ldsA, ldsB, tid); break;
            case 1: stage_tiles<128>(gA, gB, ldsA, ldsB, tid); break;
            case 2: stage_tiles<256>(gA, gB, ldsA, ldsB, tid); break;
            default: stage_tiles<384>(gA, gB, ldsA, ldsB, tid); break;
        }
        __syncthreads();                  // drain + barrier
#pragma unroll
        for (int kk = 0; kk < 4; ++kk) {  // four K=32 MFMA steps per BK=128
            long af[4], bfr[4];
#pragma unroll
            for (int im = 0; im < 4; ++im) {
                int row = wm + im * 16 + l16;
                int c4 = kk * 2 + (quad >> 1);
                int sl = c4 ^ (row & 7);
                af[im] = *(const long*)&ldsA[row * 128 + sl * 16 + (quad & 1) * 8];
            }
#pragma unroll
            for (int in = 0; in < 4; ++in) {
                int col = wn + in * 16 + l16;
                int c4 = kk * 2 + (quad >> 1);
                int sl = c4 ^ (col & 7);
                bfr[in] = *(const long*)&ldsB[col * 128 + sl * 16 + (quad & 1) * 8];
            }
#pragma unroll
            for (int im = 0; im < 4; ++im)
#pragma unroll
                for (int in = 0; in < 4; ++in)
                    acc[im][in] = __builtin_amdgcn_mfma_f32_16x16x32_fp8_fp8(
                        af[im], bfr[in], acc[im][in], 0, 0, 0);
        }
        __syncthreads();                  // protect buffers before next stage
    }

    // ---------------- epilogue (acc already = sim/T * log2e) ----------------
    int lc[4];
#pragma unroll
    for (int in = 0; in < 4; ++in) lc[in] = labC[wn + in * 16 + l16];

    float colT[4] = {0.f, 0.f, 0.f, 0.f}, colP[4] = {0.f, 0.f, 0.f, 0.f};
#pragma unroll
    for (int im = 0; im < 4; ++im) {
        float rowT[4] = {0.f, 0.f, 0.f, 0.f}, rowP[4] = {0.f, 0.f, 0.f, 0.f};
#pragma unroll
        for (int reg = 0; reg < 4; ++reg) {
            int rloc = wm + im * 16 + quad * 4 + reg;
            int li = labR[rloc];
#pragma unroll
            for (int in = 0; in < 4; ++in) {
                int cloc = wn + in * 16 + l16;
                float e = __builtin_exp2f(acc[im][in][reg]);  // v_exp_f32, no mul
                bool pos = (lc[in] == li) && (rloc - cloc != dd);
                colT[in] += e; rowT[reg] += e;
                if (pos) { colP[in] += e; rowP[reg] += e; }
            }
        }
        if (!isDiag) {
#pragma unroll
            for (int reg = 0; reg < 4; ++reg) {
                float tt = rowT[reg], pp = rowP[reg];
                tt += __shfl_xor(tt, 1); tt += __shfl_xor(tt, 2);
                tt += __shfl_xor(tt, 4); tt += __shfl_xor(tt, 8);
                pp += __shfl_xor(pp, 1); pp += __shfl_xor(pp, 2);
                pp += __shfl_xor(pp, 4); pp += __shfl_xor(pp, 8);
                if (l16 == 0) {
                    int rloc = wm + im * 16 + quad * 4 + reg;
                    rT[wc][rloc] = tt;
                    rP[wc][rloc] = pp;
                }
            }
        }
    }
#pragma unroll
    for (int in = 0; in < 4; ++in) {
        float tt = colT[in], pp = colP[in];
        tt += __shfl_xor(tt, 16); tt += __shfl_xor(tt, 32);
        pp += __shfl_xor(pp, 16); pp += __shfl_xor(pp, 32);
        if (quad == 0) {
            int cloc = wn + in * 16 + l16;
            cT[wr][cloc] = tt;
            cP[wr][cloc] = pp;
        }
    }
    __syncthreads();
    float* rowTotal = rowTotalR + rep * N_ROWS;
    float* rowPos   = rowPosR   + rep * N_ROWS;
    if (tid < 128) {
        atomicAdd(&rowTotal[colBase + tid], cT[0][tid] + cT[1][tid]);
        if (!isDiag) atomicAdd(&rowTotal[rowBase + tid], rT[0][tid] + rT[1][tid]);
    } else {
        int t2 = tid - 128;
        atomicAdd(&rowPos[colBase + t2], cP[0][t2] + cP[1][t2]);
        if (!isDiag) atomicAdd(&rowPos[rowBase + t2], rP[0][t2] + rP[1][t2]);
    }
}

// ------- kernel 3: fold replicas + histogram + loss (64 blocks) ------------
__global__ __launch_bounds__(256) void reduce_loss_kernel(
        const int* __restrict__ labels, const float* __restrict__ rowTotalR,
        const float* __restrict__ rowPosR, float* __restrict__ out) {
    __shared__ int hist[128];
    __shared__ float red[256];
    int tid = threadIdx.x;
    if (tid < 128) hist[tid] = 0;
    __syncthreads();
    for (int i = tid; i < N_ROWS; i += 256)
        atomicAdd(&hist[labels[i] & 127], 1);
    __syncthreads();
    float sacc = 0.f;
    if (tid < 128) {
        int row = blockIdx.x * 128 + tid;
        float T = 0.f, P = 0.f;
#pragma unroll
        for (int r = 0; r < NREP; ++r) {
            T += rowTotalR[r * N_ROWS + row];
            P += rowPosR[r * N_ROWS + row];
        }
        float cc = (float)(hist[labels[row] & 127] - 1);
        sacc = logf((P / (cc + 1e-9f)) / T);
    }
    red[tid] = sacc;
    __syncthreads();
    for (int st = 128; st; st >>= 1) {
        if (tid < st) red[tid] += red[tid + st];
        __syncthreads();
    }
    if (tid == 0) atomicAdd(out, -red[0] / (float)N_ROWS);
}

extern "C" void kernel_launch(void* const* d_in, const int* in_sizes, int n_in,
                              void* d_out, int out_size, void* d_ws, size_t ws_size,
                              hipStream_t stream) {
    const float* hidden = (const float*)d_in[0];
    const int* labels   = (const int*)d_in[1];
    float* out = (float*)d_out;

    char* ws = (char*)d_ws;
    char* hb8 = ws;                                          // 8192*512 = 4 MB
    float* rowTotalR = (float*)(ws + (size_t)N_ROWS * DIM);  // NREP*8192 f
    float* rowPosR   = rowTotalR + NREP * N_ROWS;            // NREP*8192 f

    norm_cast_kernel<<<N_ROWS / 4, 256, 0, stream>>>(hidden, (u32*)hb8, rowTotalR, out);
    tile_kernel<<<9 * 256, 256, 0, stream>>>(hb8, labels, rowTotalR, rowPosR);
    reduce_loss_kernel<<<64, 256, 0, stream>>>(labels, rowTotalR, rowPosR, out);
}

// Round 12
// 116.799 us; speedup vs baseline: 1.2289x; 1.0207x over previous
//
#include <hip/hip_runtime.h>
#include <hip/hip_bf16.h>

typedef unsigned short u16;
typedef unsigned int u32;
typedef float f32x4 __attribute__((ext_vector_type(4)));
typedef long lx2 __attribute__((ext_vector_type(2)));

#define N_ROWS 8192
#define DIM 512
#define BM 128
#define BN 128
#define NREP 8             // accumulator replicas
// sqrt(log2(e)/0.07): folded into stored fp8 so MFMA emits sim/T*log2(e)
// directly and the epilogue uses raw v_exp_f32 (exp2) with no extra mul.
#define SCALE 4.5398160f

// ------- kernel 1: L2-normalize rows -> fp8 e4m3 (pre-scaled); zero accs ---
// NEW (R11): kk-interleaved row layout. Within each 128-B k0 slice, the 8-B
// unit (kk,q) [global unit u=kk*4+q] is stored at chunk c=(kk>>1)*4+q,
// half h=kk&1. A lane's MFMA fragments for kk and kk+1 are then CONTIGUOUS
// 16 B in LDS -> tile_kernel reads b128 instead of 2x b64 (half the LDS
// instruction stream + half the address VALU).
__global__ __launch_bounds__(256) void norm_cast_kernel(
        const float* __restrict__ x, u32* __restrict__ hb8,
        float* __restrict__ accR /* 2*NREP*N_ROWS floats */,
        float* __restrict__ out) {
    int gid = blockIdx.x * 256 + threadIdx.x;
    if (gid < 2 * NREP * N_ROWS) accR[gid] = 0.f;
    if (gid == 0) out[0] = 0.f;
    int row  = blockIdx.x * 4 + (threadIdx.x >> 6);
    int lane = threadIdx.x & 63;
    const float4* xr = (const float4*)(x + (size_t)row * DIM);
    float4 v0 = xr[lane * 2 + 0];
    float4 v1 = xr[lane * 2 + 1];
    float ss = v0.x * v0.x + v0.y * v0.y + v0.z * v0.z + v0.w * v0.w
             + v1.x * v1.x + v1.y * v1.y + v1.z * v1.z + v1.w * v1.w;
#pragma unroll
    for (int off = 32; off; off >>= 1) ss += __shfl_xor(ss, off);
    float s = SCALE / fmaxf(sqrtf(ss), 1e-12f);
    // pack 8 fp8 (OCP e4m3 on gfx950, RNE+sat in HW)
    int w0 = __builtin_amdgcn_cvt_pk_fp8_f32(v0.x * s, v0.y * s, 0, false);
    w0     = __builtin_amdgcn_cvt_pk_fp8_f32(v0.z * s, v0.w * s, w0, true);
    int w1 = __builtin_amdgcn_cvt_pk_fp8_f32(v1.x * s, v1.y * s, 0, false);
    w1     = __builtin_amdgcn_cvt_pk_fp8_f32(v1.z * s, v1.w * s, w1, true);
    uint2 o; o.x = (u32)w0; o.y = (u32)w1;
    // lane = global unit index U (8 B per unit). Decompose and re-place:
    // k0 = U>>4, kk = (U>>2)&3, q = U&3 -> off = k0*128 + ((kk>>1)*4+q)*16 + (kk&1)*8
    int k0s = lane >> 4;
    int kk  = (lane >> 2) & 3;
    int q   = lane & 3;
    int noff = k0s * 128 + (((kk >> 1) * 4 + q) * 16) + ((kk & 1) * 8);
    ((uint2*)((char*)hb8 + (size_t)row * DIM + noff))[0] = o;
}

// stage helper: immediate offset must be a constant-expression for
// __builtin_amdgcn_global_load_lds -> template parameter. Layout-agnostic:
// copies 16-B chunk (sl ^ (r&7)) of each row-slice to LDS slot sl.
template <int K0OFF>
__device__ __forceinline__ void stage_tiles(
        const char* const* gA, const char* const* gB,
        char* ldsA, char* ldsB, int tid) {
#pragma unroll
    for (int s2 = 0; s2 < 4; ++s2) {
        int seg = tid + s2 * 256;
        __builtin_amdgcn_global_load_lds(
            (const __attribute__((address_space(1))) void*)gA[s2],
            (__attribute__((address_space(3))) void*)&ldsA[seg * 16],
            16, K0OFF, 0);
        __builtin_amdgcn_global_load_lds(
            (const __attribute__((address_space(1))) void*)gB[s2],
            (__attribute__((address_space(3))) void*)&ldsB[seg * 16],
            16, K0OFF, 0);
    }
}

// ------- kernel 2: triangular fused tile GEMM (fp8) + exp2 + sums ----------
// R9-MEASURED structure (51.1us tile): stage -> sync -> compute -> sync per
// BK=128; launch_bounds(256,4) -> VGPR 64+64acc, 4 blocks/CU. R11 change:
// with the kk-interleaved hb8 layout, fragment reads are ds_read_b128
// (chunk c=kk2*4+quad holds the kk=2*kk2 and kk=2*kk2+1 fragments back to
// back) -> 16 reads per BK=128 instead of 32, half the address VALU.
__global__ __launch_bounds__(256, 4) void tile_kernel(
        const char* __restrict__ hb8, const int* __restrict__ labels,
        float* __restrict__ rowTotalR, float* __restrict__ rowPosR) {
    __shared__ __align__(16) char ldsA[BM * 128];   // 16 KB
    __shared__ __align__(16) char ldsB[BN * 128];   // 16 KB
    __shared__ int labR[BM];
    __shared__ int labC[BN];
    __shared__ float cT[2][BN], cP[2][BN];
    __shared__ float rT[2][BM], rP[2][BM];

    const int b = blockIdx.x;
    const int c = b & 255;          // CU slot (round-robin)
    const int m = b >> 8;           // step 0..8
    const int y = c >> 3;
    const int p = 4 * (c & 7) + (y & 3);    // pair id [0,32)
    const int j = y >> 2;                   // CU within pair [0,8)
    const int t = j + 8 * m;                // tile index within pair
    if (t >= 65) return;
    int ti, tj;
    if (t <= p) { tj = p; ti = t; }
    else        { tj = 63 - p; ti = t - p - 1; }

    const int rowBase = ti * BM;
    const int colBase = tj * BN;
    const bool isDiag = (ti == tj);
    const int dd = colBase - rowBase;
    const int rep = (ti + tj) & (NREP - 1);
    const int tid = threadIdx.x;

    if (tid < 128) labR[tid] = labels[rowBase + tid];
    else           labC[tid - 128] = labels[colBase + tid - 128];

    const int w = tid >> 6;
    const int lane = tid & 63;
    const int wm = (w >> 1) * 64;
    const int wn = (w & 1) * 64;
    const int wr = w >> 1;
    const int wc = w & 1;
    const int quad = lane >> 4;
    const int l16 = lane & 15;

    // staging bases (computed once; k0 advances via immediate offset)
    const char* gA[4]; const char* gB[4];
#pragma unroll
    for (int s2 = 0; s2 < 4; ++s2) {
        int seg = tid + s2 * 256;         // 0..1023
        int r = seg >> 3;                 // 0..127
        int sl = seg & 7;                 // LDS 16-B slot
        int g = sl ^ (r & 7);             // global 16-B chunk within 128-B row-slice
        gA[s2] = hb8 + (size_t)(rowBase + r) * DIM + g * 16;
        gB[s2] = hb8 + (size_t)(colBase + r) * DIM + g * 16;
    }

    f32x4 acc[4][4];
#pragma unroll
    for (int i = 0; i < 4; ++i)
#pragma unroll
        for (int jj = 0; jj < 4; ++jj)
            acc[i][jj] = (f32x4){0.f, 0.f, 0.f, 0.f};

#pragma unroll
    for (int k0 = 0; k0 < 4; ++k0) {      // BK=128 bytes, imm offset k0*128
        switch (k0) {
            case 0: stage_tiles<0>(gA, gB, ldsA, ldsB, tid); break;
            case 1: stage_tiles<128>(gA, gB, ldsA, ldsB, tid); break;
            case 2: stage_tiles<256>(gA, gB, ldsA, ldsB, tid); break;
            default: stage_tiles<384>(gA, gB, ldsA, ldsB, tid); break;
        }
        __syncthreads();                  // drain + barrier
#pragma unroll
        for (int kk2 = 0; kk2 < 2; ++kk2) {   // two K=64 rounds per BK=128
            lx2 bfr[4];
#pragma unroll
            for (int in = 0; in < 4; ++in) {
                int col = wn + in * 16 + l16;
                int sl = (kk2 * 4 + quad) ^ (col & 7);
                bfr[in] = *(const lx2*)&ldsB[col * 128 + sl * 16];
            }
#pragma unroll
            for (int im = 0; im < 4; ++im) {
                int row = wm + im * 16 + l16;
                int sl = (kk2 * 4 + quad) ^ (row & 7);
                lx2 af = *(const lx2*)&ldsA[row * 128 + sl * 16];
#pragma unroll
                for (int in = 0; in < 4; ++in) {
                    acc[im][in] = __builtin_amdgcn_mfma_f32_16x16x32_fp8_fp8(
                        af.x, bfr[in].x, acc[im][in], 0, 0, 0);
                    acc[im][in] = __builtin_amdgcn_mfma_f32_16x16x32_fp8_fp8(
                        af.y, bfr[in].y, acc[im][in], 0, 0, 0);
                }
            }
        }
        __syncthreads();                  // protect buffers before next stage
    }

    // ---------------- epilogue (acc already = sim/T * log2e) ----------------
    int lc[4];
#pragma unroll
    for (int in = 0; in < 4; ++in) lc[in] = labC[wn + in * 16 + l16];

    float colT[4] = {0.f, 0.f, 0.f, 0.f}, colP[4] = {0.f, 0.f, 0.f, 0.f};
#pragma unroll
    for (int im = 0; im < 4; ++im) {
        float rowT[4] = {0.f, 0.f, 0.f, 0.f}, rowP[4] = {0.f, 0.f, 0.f, 0.f};
#pragma unroll
        for (int reg = 0; reg < 4; ++reg) {
            int rloc = wm + im * 16 + quad * 4 + reg;
            int li = labR[rloc];
#pragma unroll
            for (int in = 0; in < 4; ++in) {
                int cloc = wn + in * 16 + l16;
                float e = __builtin_exp2f(acc[im][in][reg]);  // v_exp_f32, no mul
                bool pos = (lc[in] == li) && (rloc - cloc != dd);
                colT[in] += e; rowT[reg] += e;
                if (pos) { colP[in] += e; rowP[reg] += e; }
            }
        }
        if (!isDiag) {
#pragma unroll
            for (int reg = 0; reg < 4; ++reg) {
                float tt = rowT[reg], pp = rowP[reg];
                tt += __shfl_xor(tt, 1); tt += __shfl_xor(tt, 2);
                tt += __shfl_xor(tt, 4); tt += __shfl_xor(tt, 8);
                pp += __shfl_xor(pp, 1); pp += __shfl_xor(pp, 2);
                pp += __shfl_xor(pp, 4); pp += __shfl_xor(pp, 8);
                if (l16 == 0) {
                    int rloc = wm + im * 16 + quad * 4 + reg;
                    rT[wc][rloc] = tt;
                    rP[wc][rloc] = pp;
                }
            }
        }
    }
#pragma unroll
    for (int in = 0; in < 4; ++in) {
        float tt = colT[in], pp = colP[in];
        tt += __shfl_xor(tt, 16); tt += __shfl_xor(tt, 32);
        pp += __shfl_xor(pp, 16); pp += __shfl_xor(pp, 32);
        if (quad == 0) {
            int cloc = wn + in * 16 + l16;
            cT[wr][cloc] = tt;
            cP[wr][cloc] = pp;
        }
    }
    __syncthreads();
    float* rowTotal = rowTotalR + rep * N_ROWS;
    float* rowPos   = rowPosR   + rep * N_ROWS;
    if (tid < 128) {
        atomicAdd(&rowTotal[colBase + tid], cT[0][tid] + cT[1][tid]);
        if (!isDiag) atomicAdd(&rowTotal[rowBase + tid], rT[0][tid] + rT[1][tid]);
    } else {
        int t2 = tid - 128;
        atomicAdd(&rowPos[colBase + t2], cP[0][t2] + cP[1][t2]);
        if (!isDiag) atomicAdd(&rowPos[rowBase + t2], rP[0][t2] + rP[1][t2]);
    }
}

// ------- kernel 3: fold replicas + histogram + loss (64 blocks) ------------
__global__ __launch_bounds__(256) void reduce_loss_kernel(
        const int* __restrict__ labels, const float* __restrict__ rowTotalR,
        const float* __restrict__ rowPosR, float* __restrict__ out) {
    __shared__ int hist[128];
    __shared__ float red[256];
    int tid = threadIdx.x;
    if (tid < 128) hist[tid] = 0;
    __syncthreads();
    for (int i = tid; i < N_ROWS; i += 256)
        atomicAdd(&hist[labels[i] & 127], 1);
    __syncthreads();
    float sacc = 0.f;
    if (tid < 128) {
        int row = blockIdx.x * 128 + tid;
        float T = 0.f, P = 0.f;
#pragma unroll
        for (int r = 0; r < NREP; ++r) {
            T += rowTotalR[r * N_ROWS + row];
            P += rowPosR[r * N_ROWS + row];
        }
        float cc = (float)(hist[labels[row] & 127] - 1);
        sacc = logf((P / (cc + 1e-9f)) / T);
    }
    red[tid] = sacc;
    __syncthreads();
    for (int st = 128; st; st >>= 1) {
        if (tid < st) red[tid] += red[tid + st];
        __syncthreads();
    }
    if (tid == 0) atomicAdd(out, -red[0] / (float)N_ROWS);
}

extern "C" void kernel_launch(void* const* d_in, const int* in_sizes, int n_in,
                              void* d_out, int out_size, void* d_ws, size_t ws_size,
                              hipStream_t stream) {
    const float* hidden = (const float*)d_in[0];
    const int* labels   = (const int*)d_in[1];
    float* out = (float*)d_out;

    char* ws = (char*)d_ws;
    char* hb8 = ws;                                          // 8192*512 = 4 MB
    float* rowTotalR = (float*)(ws + (size_t)N_ROWS * DIM);  // NREP*8192 f
    float* rowPosR   = rowTotalR + NREP * N_ROWS;            // NREP*8192 f

    norm_cast_kernel<<<N_ROWS / 4, 256, 0, stream>>>(hidden, (u32*)hb8, rowTotalR, out);
    tile_kernel<<<9 * 256, 256, 0, stream>>>(hb8, labels, rowTotalR, rowPosR);
    reduce_loss_kernel<<<64, 256, 0, stream>>>(labels, rowTotalR, rowPosR, out);
}

// Round 13
// 116.105 us; speedup vs baseline: 1.2363x; 1.0060x over previous
//
#include <hip/hip_runtime.h>
#include <hip/hip_bf16.h>

typedef unsigned short u16;
typedef unsigned int u32;
typedef float f32x4 __attribute__((ext_vector_type(4)));
typedef long lx2 __attribute__((ext_vector_type(2)));

#define N_ROWS 8192
#define DIM 512
#define BM 128
#define BN 128
#define NREP 8             // accumulator replicas
// sqrt(log2(e)/0.07): folded into stored fp8 so MFMA emits sim/T*log2(e)
// directly and the epilogue uses raw v_exp_f32 (exp2) with no extra mul.
#define SCALE 4.5398160f

// ------- kernel 1: L2-normalize rows -> fp8 e4m3 (pre-scaled); zero accs ---
// R11 kk-interleaved row layout (proven R12): within each 128-B k0 slice,
// unit (kk,q) stored at chunk c=(kk>>1)*4+q, half kk&1 -> lane fragments for
// kk,kk+1 are contiguous 16 B -> tile kernel reads ds_read_b128.
__global__ __launch_bounds__(256) void norm_cast_kernel(
        const float* __restrict__ x, u32* __restrict__ hb8,
        float* __restrict__ accR /* 2*NREP*N_ROWS floats */,
        float* __restrict__ out) {
    int gid = blockIdx.x * 256 + threadIdx.x;
    if (gid < 2 * NREP * N_ROWS) accR[gid] = 0.f;
    if (gid == 0) out[0] = 0.f;
    int row  = blockIdx.x * 4 + (threadIdx.x >> 6);
    int lane = threadIdx.x & 63;
    const float4* xr = (const float4*)(x + (size_t)row * DIM);
    float4 v0 = xr[lane * 2 + 0];
    float4 v1 = xr[lane * 2 + 1];
    float ss = v0.x * v0.x + v0.y * v0.y + v0.z * v0.z + v0.w * v0.w
             + v1.x * v1.x + v1.y * v1.y + v1.z * v1.z + v1.w * v1.w;
#pragma unroll
    for (int off = 32; off; off >>= 1) ss += __shfl_xor(ss, off);
    float s = SCALE / fmaxf(sqrtf(ss), 1e-12f);
    // pack 8 fp8 (OCP e4m3 on gfx950, RNE+sat in HW)
    int w0 = __builtin_amdgcn_cvt_pk_fp8_f32(v0.x * s, v0.y * s, 0, false);
    w0     = __builtin_amdgcn_cvt_pk_fp8_f32(v0.z * s, v0.w * s, w0, true);
    int w1 = __builtin_amdgcn_cvt_pk_fp8_f32(v1.x * s, v1.y * s, 0, false);
    w1     = __builtin_amdgcn_cvt_pk_fp8_f32(v1.z * s, v1.w * s, w1, true);
    uint2 o; o.x = (u32)w0; o.y = (u32)w1;
    // lane = global unit index U (8 B per unit): k0=U>>4, kk=(U>>2)&3, q=U&3
    int k0s = lane >> 4;
    int kk  = (lane >> 2) & 3;
    int q   = lane & 3;
    int noff = k0s * 128 + (((kk >> 1) * 4 + q) * 16) + ((kk & 1) * 8);
    ((uint2*)((char*)hb8 + (size_t)row * DIM + noff))[0] = o;
}

// stage helper: immediate offset must be a constant-expression for
// __builtin_amdgcn_global_load_lds -> template parameter. Layout-agnostic.
template <int K0OFF>
__device__ __forceinline__ void stage_tiles(
        const char* const* gA, const char* const* gB,
        char* ldsA, char* ldsB, int tid) {
#pragma unroll
    for (int s2 = 0; s2 < 4; ++s2) {
        int seg = tid + s2 * 256;
        __builtin_amdgcn_global_load_lds(
            (const __attribute__((address_space(1))) void*)gA[s2],
            (__attribute__((address_space(3))) void*)&ldsA[seg * 16],
            16, K0OFF, 0);
        __builtin_amdgcn_global_load_lds(
            (const __attribute__((address_space(1))) void*)gB[s2],
            (__attribute__((address_space(3))) void*)&ldsB[seg * 16],
            16, K0OFF, 0);
    }
}

// ------- kernel 2: triangular fused tile GEMM (fp8) + exp2 + sums ----------
// R12-MEASURED structure (48.7us tile): stage -> sync -> compute -> sync per
// BK=128, b128 fragment reads (0 bank conflicts), launch_bounds(256,4).
// R13 change (identity): hand-hoisted LDS addressing. col&7==l16&7 (wn,in*16
// are x16) -> swizzle XOR is im/in-invariant; every fragment addr = per-lane
// base + COMPILE-TIME offset im*2048, kk2 flips one bit (base^64). Inner loop
// is now pure ds_read_b128 + MFMA (no per-read address VALU).
__global__ __launch_bounds__(256, 4) void tile_kernel(
        const char* __restrict__ hb8, const int* __restrict__ labels,
        float* __restrict__ rowTotalR, float* __restrict__ rowPosR) {
    __shared__ __align__(16) char ldsA[BM * 128];   // 16 KB
    __shared__ __align__(16) char ldsB[BN * 128];   // 16 KB
    __shared__ int labR[BM];
    __shared__ int labC[BN];
    __shared__ float cT[2][BN], cP[2][BN];
    __shared__ float rT[2][BM], rP[2][BM];

    const int b = blockIdx.x;
    const int c = b & 255;          // CU slot (round-robin)
    const int m = b >> 8;           // step 0..8
    const int y = c >> 3;
    const int p = 4 * (c & 7) + (y & 3);    // pair id [0,32)
    const int j = y >> 2;                   // CU within pair [0,8)
    const int t = j + 8 * m;                // tile index within pair
    if (t >= 65) return;
    int ti, tj;
    if (t <= p) { tj = p; ti = t; }
    else        { tj = 63 - p; ti = t - p - 1; }

    const int rowBase = ti * BM;
    const int colBase = tj * BN;
    const bool isDiag = (ti == tj);
    const int dd = colBase - rowBase;
    const int rep = (ti + tj) & (NREP - 1);
    const int tid = threadIdx.x;

    if (tid < 128) labR[tid] = labels[rowBase + tid];
    else           labC[tid - 128] = labels[colBase + tid - 128];

    const int w = tid >> 6;
    const int lane = tid & 63;
    const int wm = (w >> 1) * 64;
    const int wn = (w & 1) * 64;
    const int wr = w >> 1;
    const int wc = w & 1;
    const int quad = lane >> 4;
    const int l16 = lane & 15;

    // hoisted per-lane LDS fragment bases (kk2=0); kk2=1 is base^64
    const int slx = quad ^ (l16 & 7);
    const int offA0 = (wm + l16) * 128 + slx * 16;
    const int offB0 = (wn + l16) * 128 + slx * 16;

    // staging bases (computed once; k0 advances via immediate offset)
    const char* gA[4]; const char* gB[4];
#pragma unroll
    for (int s2 = 0; s2 < 4; ++s2) {
        int seg = tid + s2 * 256;         // 0..1023
        int r = seg >> 3;                 // 0..127
        int sl = seg & 7;                 // LDS 16-B slot
        int g = sl ^ (r & 7);             // global 16-B chunk within 128-B row-slice
        gA[s2] = hb8 + (size_t)(rowBase + r) * DIM + g * 16;
        gB[s2] = hb8 + (size_t)(colBase + r) * DIM + g * 16;
    }

    f32x4 acc[4][4];
#pragma unroll
    for (int i = 0; i < 4; ++i)
#pragma unroll
        for (int jj = 0; jj < 4; ++jj)
            acc[i][jj] = (f32x4){0.f, 0.f, 0.f, 0.f};

#pragma unroll
    for (int k0 = 0; k0 < 4; ++k0) {      // BK=128 bytes, imm offset k0*128
        switch (k0) {
            case 0: stage_tiles<0>(gA, gB, ldsA, ldsB, tid); break;
            case 1: stage_tiles<128>(gA, gB, ldsA, ldsB, tid); break;
            case 2: stage_tiles<256>(gA, gB, ldsA, ldsB, tid); break;
            default: stage_tiles<384>(gA, gB, ldsA, ldsB, tid); break;
        }
        __syncthreads();                  // drain + barrier
#pragma unroll
        for (int kk2 = 0; kk2 < 2; ++kk2) {   // two K=64 rounds per BK=128
            const int oA = kk2 ? (offA0 ^ 64) : offA0;
            const int oB = kk2 ? (offB0 ^ 64) : offB0;
            lx2 bfr[4];
#pragma unroll
            for (int in = 0; in < 4; ++in)
                bfr[in] = *(const lx2*)&ldsB[oB + in * 2048];
#pragma unroll
            for (int im = 0; im < 4; ++im) {
                lx2 af = *(const lx2*)&ldsA[oA + im * 2048];
#pragma unroll
                for (int in = 0; in < 4; ++in) {
                    acc[im][in] = __builtin_amdgcn_mfma_f32_16x16x32_fp8_fp8(
                        af.x, bfr[in].x, acc[im][in], 0, 0, 0);
                    acc[im][in] = __builtin_amdgcn_mfma_f32_16x16x32_fp8_fp8(
                        af.y, bfr[in].y, acc[im][in], 0, 0, 0);
                }
            }
        }
        __syncthreads();                  // protect buffers before next stage
    }

    // ---------------- epilogue (acc already = sim/T * log2e) ----------------
    int lc[4];
#pragma unroll
    for (int in = 0; in < 4; ++in) lc[in] = labC[wn + in * 16 + l16];

    float colT[4] = {0.f, 0.f, 0.f, 0.f}, colP[4] = {0.f, 0.f, 0.f, 0.f};
#pragma unroll
    for (int im = 0; im < 4; ++im) {
        float rowT[4] = {0.f, 0.f, 0.f, 0.f}, rowP[4] = {0.f, 0.f, 0.f, 0.f};
#pragma unroll
        for (int reg = 0; reg < 4; ++reg) {
            int rloc = wm + im * 16 + quad * 4 + reg;
            int li = labR[rloc];
#pragma unroll
            for (int in = 0; in < 4; ++in) {
                int cloc = wn + in * 16 + l16;
                float e = __builtin_exp2f(acc[im][in][reg]);  // v_exp_f32, no mul
                bool pos = (lc[in] == li) && (rloc - cloc != dd);
                colT[in] += e; rowT[reg] += e;
                if (pos) { colP[in] += e; rowP[reg] += e; }
            }
        }
        if (!isDiag) {
#pragma unroll
            for (int reg = 0; reg < 4; ++reg) {
                float tt = rowT[reg], pp = rowP[reg];
                tt += __shfl_xor(tt, 1); tt += __shfl_xor(tt, 2);
                tt += __shfl_xor(tt, 4); tt += __shfl_xor(tt, 8);
                pp += __shfl_xor(pp, 1); pp += __shfl_xor(pp, 2);
                pp += __shfl_xor(pp, 4); pp += __shfl_xor(pp, 8);
                if (l16 == 0) {
                    int rloc = wm + im * 16 + quad * 4 + reg;
                    rT[wc][rloc] = tt;
                    rP[wc][rloc] = pp;
                }
            }
        }
    }
#pragma unroll
    for (int in = 0; in < 4; ++in) {
        float tt = colT[in], pp = colP[in];
        tt += __shfl_xor(tt, 16); tt += __shfl_xor(tt, 32);
        pp += __shfl_xor(pp, 16); pp += __shfl_xor(pp, 32);
        if (quad == 0) {
            int cloc = wn + in * 16 + l16;
            cT[wr][cloc] = tt;
            cP[wr][cloc] = pp;
        }
    }
    __syncthreads();
    float* rowTotal = rowTotalR + rep * N_ROWS;
    float* rowPos   = rowPosR   + rep * N_ROWS;
    if (tid < 128) {
        atomicAdd(&rowTotal[colBase + tid], cT[0][tid] + cT[1][tid]);
        if (!isDiag) atomicAdd(&rowTotal[rowBase + tid], rT[0][tid] + rT[1][tid]);
    } else {
        int t2 = tid - 128;
        atomicAdd(&rowPos[colBase + t2], cP[0][t2] + cP[1][t2]);
        if (!isDiag) atomicAdd(&rowPos[rowBase + t2], rP[0][t2] + rP[1][t2]);
    }
}

// ------- kernel 3: fold replicas + histogram + loss (64 blocks) ------------
__global__ __launch_bounds__(256) void reduce_loss_kernel(
        const int* __restrict__ labels, const float* __restrict__ rowTotalR,
        const float* __restrict__ rowPosR, float* __restrict__ out) {
    __shared__ int hist[128];
    __shared__ float red[256];
    int tid = threadIdx.x;
    if (tid < 128) hist[tid] = 0;
    __syncthreads();
    for (int i = tid; i < N_ROWS; i += 256)
        atomicAdd(&hist[labels[i] & 127], 1);
    __syncthreads();
    float sacc = 0.f;
    if (tid < 128) {
        int row = blockIdx.x * 128 + tid;
        float T = 0.f, P = 0.f;
#pragma unroll
        for (int r = 0; r < NREP; ++r) {
            T += rowTotalR[r * N_ROWS + row];
            P += rowPosR[r * N_ROWS + row];
        }
        float cc = (float)(hist[labels[row] & 127] - 1);
        sacc = logf((P / (cc + 1e-9f)) / T);
    }
    red[tid] = sacc;
    __syncthreads();
    for (int st = 128; st; st >>= 1) {
        if (tid < st) red[tid] += red[tid + st];
        __syncthreads();
    }
    if (tid == 0) atomicAdd(out, -red[0] / (float)N_ROWS);
}

extern "C" void kernel_launch(void* const* d_in, const int* in_sizes, int n_in,
                              void* d_out, int out_size, void* d_ws, size_t ws_size,
                              hipStream_t stream) {
    const float* hidden = (const float*)d_in[0];
    const int* labels   = (const int*)d_in[1];
    float* out = (float*)d_out;

    char* ws = (char*)d_ws;
    char* hb8 = ws;                                          // 8192*512 = 4 MB
    float* rowTotalR = (float*)(ws + (size_t)N_ROWS * DIM);  // NREP*8192 f
    float* rowPosR   = rowTotalR + NREP * N_ROWS;            // NREP*8192 f

    norm_cast_kernel<<<N_ROWS / 4, 256, 0, stream>>>(hidden, (u32*)hb8, rowTotalR, out);
    tile_kernel<<<9 * 256, 256, 0, stream>>>(hb8, labels, rowTotalR, rowPosR);
    reduce_loss_kernel<<<64, 256, 0, stream>>>(labels, rowTotalR, rowPosR, out);
}

// Round 14
// 115.582 us; speedup vs baseline: 1.2418x; 1.0045x over previous
//
#include <hip/hip_runtime.h>
#include <hip/hip_bf16.h>

typedef unsigned short u16;
typedef unsigned int u32;
typedef float f32x4 __attribute__((ext_vector_type(4)));
typedef long lx2 __attribute__((ext_vector_type(2)));

#define N_ROWS 8192
#define DIM 512
#define BM 128
#define BN 128
#define NREP 8             // accumulator replicas
// sqrt(log2(e)/0.07): folded into stored fp8 so MFMA emits sim/T*log2(e)
// directly and the epilogue uses raw v_exp_f32 (exp2) with no extra mul.
#define SCALE 4.5398160f

// ------- kernel 1: L2-normalize rows -> fp8 e4m3 (pre-scaled); zero accs ---
// R11 kk-interleaved row layout (proven R12): within each 128-B k0 slice,
// unit (kk,q) stored at byte (kk>>1)*64 + q*16 + (kk&1)*8 -> the 64-B range
// [s*64, s*64+64) holds exactly K-elements [s*64, (s+1)*64) with lane
// fragments (kk,kk+1 | quad q) contiguous 16 B -> ds_read_b128 in tile.
__global__ __launch_bounds__(256) void norm_cast_kernel(
        const float* __restrict__ x, u32* __restrict__ hb8,
        float* __restrict__ accR /* 2*NREP*N_ROWS floats */,
        float* __restrict__ out) {
    int gid = blockIdx.x * 256 + threadIdx.x;
    if (gid < 2 * NREP * N_ROWS) accR[gid] = 0.f;
    if (gid == 0) out[0] = 0.f;
    int row  = blockIdx.x * 4 + (threadIdx.x >> 6);
    int lane = threadIdx.x & 63;
    const float4* xr = (const float4*)(x + (size_t)row * DIM);
    float4 v0 = xr[lane * 2 + 0];
    float4 v1 = xr[lane * 2 + 1];
    float ss = v0.x * v0.x + v0.y * v0.y + v0.z * v0.z + v0.w * v0.w
             + v1.x * v1.x + v1.y * v1.y + v1.z * v1.z + v1.w * v1.w;
#pragma unroll
    for (int off = 32; off; off >>= 1) ss += __shfl_xor(ss, off);
    float s = SCALE / fmaxf(sqrtf(ss), 1e-12f);
    // pack 8 fp8 (OCP e4m3 on gfx950, RNE+sat in HW)
    int w0 = __builtin_amdgcn_cvt_pk_fp8_f32(v0.x * s, v0.y * s, 0, false);
    w0     = __builtin_amdgcn_cvt_pk_fp8_f32(v0.z * s, v0.w * s, w0, true);
    int w1 = __builtin_amdgcn_cvt_pk_fp8_f32(v1.x * s, v1.y * s, 0, false);
    w1     = __builtin_amdgcn_cvt_pk_fp8_f32(v1.z * s, v1.w * s, w1, true);
    uint2 o; o.x = (u32)w0; o.y = (u32)w1;
    // lane = global unit index U (8 B per unit): k0=U>>4, kk=(U>>2)&3, q=U&3
    int k0s = lane >> 4;
    int kk  = (lane >> 2) & 3;
    int q   = lane & 3;
    int noff = k0s * 128 + (((kk >> 1) * 4 + q) * 16) + ((kk & 1) * 8);
    ((uint2*)((char*)hb8 + (size_t)row * DIM + noff))[0] = o;
}

// stage helper (BK=64): per step each thread copies 2 A-chunks + 2 B-chunks
// (512 chunks x 16 B = 8 KB per matrix). Imm offset = step*64 via template.
template <int SOFF>
__device__ __forceinline__ void stage_tiles(
        const char* const* gA, const char* const* gB,
        char* ldsA, char* ldsB, int tid) {
#pragma unroll
    for (int s2 = 0; s2 < 2; ++s2) {
        int seg = tid + s2 * 256;          // 0..511
        __builtin_amdgcn_global_load_lds(
            (const __attribute__((address_space(1))) void*)gA[s2],
            (__attribute__((address_space(3))) void*)&ldsA[seg * 16],
            16, SOFF, 0);
        __builtin_amdgcn_global_load_lds(
            (const __attribute__((address_space(1))) void*)gB[s2],
            (__attribute__((address_space(3))) void*)&ldsB[seg * 16],
            16, SOFF, 0);
    }
}

// ------- kernel 2: triangular fused tile GEMM (fp8) + exp2 + sums ----------
// R12/R13-proven core semantics (b128 frag reads, 0 bank conflicts, hoisted
// addressing, launch_bounds(256,4)). R14 change: BK=64 staging (m97-proven
// geometry) -> LDS 21.5 KB/block -> 7 blocks/CU (was 4 at 37.9 KB). The only
// lever that has moved this kernel is co-residency (R8/R9); this doubles the
// wait-hiding capacity. Barriers 8 -> 16/tile (hidden by 28-wave/CU pool).
// LDS rows 64 B, 4 slots; stage swizzle g = sl ^ ((r>>1)&3), read slot
// = quad ^ ((l16>>1)&3) — same involution both sides, 2-way max aliasing.
__global__ __launch_bounds__(256, 4) void tile_kernel(
        const char* __restrict__ hb8, const int* __restrict__ labels,
        float* __restrict__ rowTotalR, float* __restrict__ rowPosR) {
    __shared__ __align__(16) char ldsA[BM * 64];    // 8 KB
    __shared__ __align__(16) char ldsB[BN * 64];    // 8 KB
    __shared__ int labR[BM];
    __shared__ int labC[BN];
    __shared__ float cT[2][BN], cP[2][BN];
    __shared__ float rT[2][BM], rP[2][BM];

    const int b = blockIdx.x;
    const int c = b & 255;          // CU slot (round-robin)
    const int m = b >> 8;           // step 0..8
    const int y = c >> 3;
    const int p = 4 * (c & 7) + (y & 3);    // pair id [0,32)
    const int j = y >> 2;                   // CU within pair [0,8)
    const int t = j + 8 * m;                // tile index within pair
    if (t >= 65) return;
    int ti, tj;
    if (t <= p) { tj = p; ti = t; }
    else        { tj = 63 - p; ti = t - p - 1; }

    const int rowBase = ti * BM;
    const int colBase = tj * BN;
    const bool isDiag = (ti == tj);
    const int dd = colBase - rowBase;
    const int rep = (ti + tj) & (NREP - 1);
    const int tid = threadIdx.x;

    if (tid < 128) labR[tid] = labels[rowBase + tid];
    else           labC[tid - 128] = labels[colBase + tid - 128];

    const int w = tid >> 6;
    const int lane = tid & 63;
    const int wm = (w >> 1) * 64;
    const int wn = (w & 1) * 64;
    const int wr = w >> 1;
    const int wc = w & 1;
    const int quad = lane >> 4;
    const int l16 = lane & 15;

    // hoisted per-lane LDS fragment bases: row stride 64 B, slot swizzle
    // quad ^ ((l16>>1)&3); im advances 16 rows = 1024 B (imm offset).
    const int slx = quad ^ ((l16 >> 1) & 3);
    const int offA = (wm + l16) * 64 + slx * 16;
    const int offB = (wn + l16) * 64 + slx * 16;

    // staging bases (computed once; step advances via immediate offset)
    const char* gA[2]; const char* gB[2];
#pragma unroll
    for (int s2 = 0; s2 < 2; ++s2) {
        int seg = tid + s2 * 256;         // 0..511
        int r = seg >> 2;                 // 0..127
        int sl = seg & 3;                 // LDS 16-B slot within 64-B row
        int g = sl ^ ((r >> 1) & 3);      // global 16-B chunk within 64-B step-slice
        gA[s2] = hb8 + (size_t)(rowBase + r) * DIM + g * 16;
        gB[s2] = hb8 + (size_t)(colBase + r) * DIM + g * 16;
    }

    f32x4 acc[4][4];
#pragma unroll
    for (int i = 0; i < 4; ++i)
#pragma unroll
        for (int jj = 0; jj < 4; ++jj)
            acc[i][jj] = (f32x4){0.f, 0.f, 0.f, 0.f};

#pragma unroll
    for (int s = 0; s < 8; ++s) {         // BK=64 bytes per step, imm s*64
        switch (s) {
            case 0: stage_tiles<0>(gA, gB, ldsA, ldsB, tid); break;
            case 1: stage_tiles<64>(gA, gB, ldsA, ldsB, tid); break;
            case 2: stage_tiles<128>(gA, gB, ldsA, ldsB, tid); break;
            case 3: stage_tiles<192>(gA, gB, ldsA, ldsB, tid); break;
            case 4: stage_tiles<256>(gA, gB, ldsA, ldsB, tid); break;
            case 5: stage_tiles<320>(gA, gB, ldsA, ldsB, tid); break;
            case 6: stage_tiles<384>(gA, gB, ldsA, ldsB, tid); break;
            default: stage_tiles<448>(gA, gB, ldsA, ldsB, tid); break;
        }
        __syncthreads();                  // drain + barrier
        lx2 bfr[4];
#pragma unroll
        for (int in = 0; in < 4; ++in)
            bfr[in] = *(const lx2*)&ldsB[offB + in * 1024];
#pragma unroll
        for (int im = 0; im < 4; ++im) {
            lx2 af = *(const lx2*)&ldsA[offA + im * 1024];
#pragma unroll
            for (int in = 0; in < 4; ++in) {
                acc[im][in] = __builtin_amdgcn_mfma_f32_16x16x32_fp8_fp8(
                    af.x, bfr[in].x, acc[im][in], 0, 0, 0);
                acc[im][in] = __builtin_amdgcn_mfma_f32_16x16x32_fp8_fp8(
                    af.y, bfr[in].y, acc[im][in], 0, 0, 0);
            }
        }
        __syncthreads();                  // protect buffers before next stage
    }

    // ---------------- epilogue (acc already = sim/T * log2e) ----------------
    int lc[4];
#pragma unroll
    for (int in = 0; in < 4; ++in) lc[in] = labC[wn + in * 16 + l16];

    float colT[4] = {0.f, 0.f, 0.f, 0.f}, colP[4] = {0.f, 0.f, 0.f, 0.f};
#pragma unroll
    for (int im = 0; im < 4; ++im) {
        float rowT[4] = {0.f, 0.f, 0.f, 0.f}, rowP[4] = {0.f, 0.f, 0.f, 0.f};
#pragma unroll
        for (int reg = 0; reg < 4; ++reg) {
            int rloc = wm + im * 16 + quad * 4 + reg;
            int li = labR[rloc];
#pragma unroll
            for (int in = 0; in < 4; ++in) {
                int cloc = wn + in * 16 + l16;
                float e = __builtin_exp2f(acc[im][in][reg]);  // v_exp_f32, no mul
                bool pos = (lc[in] == li) && (rloc - cloc != dd);
                colT[in] += e; rowT[reg] += e;
                if (pos) { colP[in] += e; rowP[reg] += e; }
            }
        }
        if (!isDiag) {
#pragma unroll
            for (int reg = 0; reg < 4; ++reg) {
                float tt = rowT[reg], pp = rowP[reg];
                tt += __shfl_xor(tt, 1); tt += __shfl_xor(tt, 2);
                tt += __shfl_xor(tt, 4); tt += __shfl_xor(tt, 8);
                pp += __shfl_xor(pp, 1); pp += __shfl_xor(pp, 2);
                pp += __shfl_xor(pp, 4); pp += __shfl_xor(pp, 8);
                if (l16 == 0) {
                    int rloc = wm + im * 16 + quad * 4 + reg;
                    rT[wc][rloc] = tt;
                    rP[wc][rloc] = pp;
                }
            }
        }
    }
#pragma unroll
    for (int in = 0; in < 4; ++in) {
        float tt = colT[in], pp = colP[in];
        tt += __shfl_xor(tt, 16); tt += __shfl_xor(tt, 32);
        pp += __shfl_xor(pp, 16); pp += __shfl_xor(pp, 32);
        if (quad == 0) {
            int cloc = wn + in * 16 + l16;
            cT[wr][cloc] = tt;
            cP[wr][cloc] = pp;
        }
    }
    __syncthreads();
    float* rowTotal = rowTotalR + rep * N_ROWS;
    float* rowPos   = rowPosR   + rep * N_ROWS;
    if (tid < 128) {
        atomicAdd(&rowTotal[colBase + tid], cT[0][tid] + cT[1][tid]);
        if (!isDiag) atomicAdd(&rowTotal[rowBase + tid], rT[0][tid] + rT[1][tid]);
    } else {
        int t2 = tid - 128;
        atomicAdd(&rowPos[colBase + t2], cP[0][t2] + cP[1][t2]);
        if (!isDiag) atomicAdd(&rowPos[rowBase + t2], rP[0][t2] + rP[1][t2]);
    }
}

// ------- kernel 3: fold replicas + histogram + loss (64 blocks) ------------
__global__ __launch_bounds__(256) void reduce_loss_kernel(
        const int* __restrict__ labels, const float* __restrict__ rowTotalR,
        const float* __restrict__ rowPosR, float* __restrict__ out) {
    __shared__ int hist[128];
    __shared__ float red[256];
    int tid = threadIdx.x;
    if (tid < 128) hist[tid] = 0;
    __syncthreads();
    for (int i = tid; i < N_ROWS; i += 256)
        atomicAdd(&hist[labels[i] & 127], 1);
    __syncthreads();
    float sacc = 0.f;
    if (tid < 128) {
        int row = blockIdx.x * 128 + tid;
        float T = 0.f, P = 0.f;
#pragma unroll
        for (int r = 0; r < NREP; ++r) {
            T += rowTotalR[r * N_ROWS + row];
            P += rowPosR[r * N_ROWS + row];
        }
        float cc = (float)(hist[labels[row] & 127] - 1);
        sacc = logf((P / (cc + 1e-9f)) / T);
    }
    red[tid] = sacc;
    __syncthreads();
    for (int st = 128; st; st >>= 1) {
        if (tid < st) red[tid] += red[tid + st];
        __syncthreads();
    }
    if (tid == 0) atomicAdd(out, -red[0] / (float)N_ROWS);
}

extern "C" void kernel_launch(void* const* d_in, const int* in_sizes, int n_in,
                              void* d_out, int out_size, void* d_ws, size_t ws_size,
                              hipStream_t stream) {
    const float* hidden = (const float*)d_in[0];
    const int* labels   = (const int*)d_in[1];
    float* out = (float*)d_out;

    char* ws = (char*)d_ws;
    char* hb8 = ws;                                          // 8192*512 = 4 MB
    float* rowTotalR = (float*)(ws + (size_t)N_ROWS * DIM);  // NREP*8192 f
    float* rowPosR   = rowTotalR + NREP * N_ROWS;            // NREP*8192 f

    norm_cast_kernel<<<N_ROWS / 4, 256, 0, stream>>>(hidden, (u32*)hb8, rowTotalR, out);
    tile_kernel<<<9 * 256, 256, 0, stream>>>(hb8, labels, rowTotalR, rowPosR);
    reduce_loss_kernel<<<64, 256, 0, stream>>>(labels, rowTotalR, rowPosR, out);
}